// Round 12
// baseline (125.429 us; speedup 1.0000x reference)
//
#include <hip/hip_runtime.h>

// Problem constants (from reference)
constexpr int B = 16384;
constexpr int T = 256;
constexpr int D = 8;
constexpr int F = 512;
constexpr int C = 16;
constexpr int L = 256;  // 2^D

typedef float f32x4 __attribute__((ext_vector_type(4)));

struct FP { int fidx; float thr; };  // packed per-(t,d) node info, 8 B

__device__ __forceinline__ unsigned int bf16_rne(float f) {
    const unsigned int u = __float_as_uint(f);
    return (u + 0x7fffu + ((u >> 16) & 1u)) >> 16;
}

// Kernel 1 (fused prep): blocks [0,512) do per-(t,d) argmax -> packed table;
// blocks [512,1024) convert responses fp32 -> packed bf16 pairs (RNE).
__global__ __launch_bounds__(256) void prep_kernel(
    const float* __restrict__ fw,      // (T, D, F)
    const float* __restrict__ thr,     // (T, D)
    const float* __restrict__ resp,    // (T*L*C)
    FP* __restrict__ packed,           // (T*D)
    unsigned int* __restrict__ rb)     // (T*L*C/2) bf16 pairs
{
    if (blockIdx.x < 512) {
        // argmax over F=512, first-occurrence tie-break (jnp.argmax)
        const int wave = threadIdx.x >> 6;
        const int lane = threadIdx.x & 63;
        const int row  = blockIdx.x * 4 + wave;          // [0, T*D)
        const float* base = fw + (size_t)row * F;

        float best = -INFINITY;
        int bidx = 0;
#pragma unroll
        for (int k = 0; k < F / 64; ++k) {
            const int idx = lane + k * 64;
            const float v = base[idx];
            if (v > best) { best = v; bidx = idx; }
        }
#pragma unroll
        for (int off = 32; off >= 1; off >>= 1) {
            const float ov = __shfl_xor(best, off);
            const int   oi = __shfl_xor(bidx, off);
            if (ov > best || (ov == best && oi < bidx)) { best = ov; bidx = oi; }
        }
        if (lane == 0) {
            FP p;
            p.fidx = bidx;
            p.thr  = thr[row];
            packed[row] = p;
        }
    } else {
        // responses fp32 -> bf16, 8 floats per thread
        const int i = (blockIdx.x - 512) * 256 + threadIdx.x;
        const float4* s = reinterpret_cast<const float4*>(resp) + i * 2;
        const float4 a = s[0], b = s[1];
        uint4 o;
        o.x = bf16_rne(a.x) | (bf16_rne(a.y) << 16);
        o.y = bf16_rne(a.z) | (bf16_rne(a.w) << 16);
        o.z = bf16_rne(b.x) | (bf16_rne(b.y) << 16);
        o.w = bf16_rne(b.z) | (bf16_rne(b.w) << 16);
        reinterpret_cast<uint4*>(rb)[i] = o;
    }
}

// Kernel 2: identical to round 11 (4 samples/block, one barrier,
// wave-autonomous decide+exchange+gather). Launched TWICE this round as a
// self-timing probe: dur_us_delta vs R11 == one forest_kernel duration.
__global__ __launch_bounds__(256, 4) void forest_kernel(
    const float* __restrict__ x,            // (B, F)
    const FP* __restrict__ packed,          // (T*D)
    const unsigned short* __restrict__ rb,  // bf16 (T, L, C)
    float* __restrict__ out)                // (B, C)
{
    __shared__ float xrow[4][F];   // 8 KB
    __shared__ int2  tbl[D][T];    // 16 KB: tbl[d][t] = {fidx, thr-bits}

    const int b0  = blockIdx.x * 4;
    const int tid = threadIdx.x;

    // Stage x rows: 512 float4, 2 per thread, coalesced; b128 LDS writes.
    {
        const float4* xs = reinterpret_cast<const float4*>(x + (size_t)b0 * F);
        float4* xl = reinterpret_cast<float4*>(&xrow[0][0]);
        xl[tid]       = xs[tid];
        xl[tid + 256] = xs[tid + 256];
    }
    // Stage node table transposed: thread tid reads tree tid's row (64 B
    // coalesced) and scatters to tbl[d][tid] (stride-8B lanes: conflict-free).
    {
        const int4* tp = reinterpret_cast<const int4*>(packed + (size_t)tid * D);
        const int4 q0 = tp[0], q1 = tp[1], q2 = tp[2], q3 = tp[3];
        tbl[0][tid] = make_int2(q0.x, q0.y);
        tbl[1][tid] = make_int2(q0.z, q0.w);
        tbl[2][tid] = make_int2(q1.x, q1.y);
        tbl[3][tid] = make_int2(q1.z, q1.w);
        tbl[4][tid] = make_int2(q2.x, q2.y);
        tbl[5][tid] = make_int2(q2.z, q2.w);
        tbl[6][tid] = make_int2(q3.x, q3.y);
        tbl[7][tid] = make_int2(q3.z, q3.w);
    }
    __syncthreads();   // the ONLY barrier

    const int w    = tid >> 6;
    const int lane = tid & 63;

    // ---- decide: trees 4*lane .. 4*lane+3, sample b0+w ----
    const float* xb = &xrow[w][0];
    unsigned int dec = 0;   // byte i = decision of tree 4*lane+i
#pragma unroll
    for (int d = 0; d < D; ++d) {
        const int4 a = *reinterpret_cast<const int4*>(&tbl[d][4 * lane]);
        const int4 b = *reinterpret_cast<const int4*>(&tbl[d][4 * lane + 2]);
        const unsigned int bit = 128u >> d;       // powers = 2^(D-1-d)
        if (xb[a.x] > __int_as_float(a.y)) dec |= bit;
        if (xb[a.z] > __int_as_float(a.w)) dec |= bit << 8;
        if (xb[b.x] > __int_as_float(b.y)) dec |= bit << 16;
        if (xb[b.z] > __int_as_float(b.w)) dec |= bit << 24;
    }

    // ---- exchange: lane (slot s=lane>>2, quad q=lane&3) needs, for kk,
    // tree 16kk+s = word from lane 4kk+(s>>2), byte s&3. 16 shfls, no LDS.
    const int src  = lane >> 4;                   // (s>>2)
    const int bsel = ((lane >> 2) & 3) * 8;       // (s&3)*8
    int dw[16];
#pragma unroll
    for (int kk = 0; kk < 16; ++kk) dw[kk] = __shfl((int)dec, 4 * kk + src);

    // ---- gather: ushort index = kk<<16 | s<<12 | dd<<4 | q<<2 ----
    const int lbase = ((lane >> 2) << 12) | ((lane & 3) << 2);

    uint2 r[16];
#pragma unroll
    for (int kk = 0; kk < 16; ++kk) {
        const int dd = (dw[kk] >> bsel) & 255;
        r[kk] = *reinterpret_cast<const uint2*>(rb + (kk << 16) + (dd << 4) + lbase);
    }

    float4 acc = make_float4(0.f, 0.f, 0.f, 0.f);
#pragma unroll
    for (int kk = 0; kk < 16; ++kk) {
        acc.x += __uint_as_float(r[kk].x << 16);
        acc.y += __uint_as_float(r[kk].x & 0xffff0000u);
        acc.z += __uint_as_float(r[kk].y << 16);
        acc.w += __uint_as_float(r[kk].y & 0xffff0000u);
    }

    // reduce across tree-slot bits (lane bits 2..5)
#pragma unroll
    for (int off = 4; off <= 32; off <<= 1) {
        acc.x += __shfl_xor(acc.x, off);
        acc.y += __shfl_xor(acc.y, off);
        acc.z += __shfl_xor(acc.z, off);
        acc.w += __shfl_xor(acc.w, off);
    }

    if (lane < 4) {
        const float sc = 1.0f / T;
        f32x4 o = { acc.x * sc, acc.y * sc, acc.z * sc, acc.w * sc };
        *reinterpret_cast<f32x4*>(out + ((size_t)(b0 + w) << 4) + (lane << 2)) = o;
    }
}

extern "C" void kernel_launch(void* const* d_in, const int* in_sizes, int n_in,
                              void* d_out, int out_size, void* d_ws, size_t ws_size,
                              hipStream_t stream) {
    const float* x         = (const float*)d_in[0];  // (B, F)
    const float* fw        = (const float*)d_in[1];  // (T, D, F)
    const float* thr       = (const float*)d_in[2];  // (T, D)
    const float* responses = (const float*)d_in[3];  // (T, L, C)
    float* out             = (float*)d_out;          // (B, C)

    FP* packed        = (FP*)d_ws;                                 // 16 KB
    unsigned int* rb  = (unsigned int*)((char*)d_ws + (1 << 16));  // 2 MB bf16

    prep_kernel<<<1024, 256, 0, stream>>>(fw, thr, responses, packed, rb);
    // Launched twice on purpose (self-timing probe): second launch recomputes
    // identical outputs from unchanged inputs. dur_us - 100.8 == one forest.
    forest_kernel<<<B / 4, 256, 0, stream>>>(x, packed,
                                             (const unsigned short*)rb, out);
    forest_kernel<<<B / 4, 256, 0, stream>>>(x, packed,
                                             (const unsigned short*)rb, out);
}

// Round 13
// 101.135 us; speedup vs baseline: 1.2402x; 1.2402x over previous
//
#include <hip/hip_runtime.h>

// Problem constants (from reference)
constexpr int B = 16384;
constexpr int T = 256;
constexpr int D = 8;
constexpr int F = 512;
constexpr int C = 16;
constexpr int L = 256;  // 2^D

typedef float f32x4 __attribute__((ext_vector_type(4)));

struct FP { int fidx; float thr; };  // packed per-(t,d) node info, 8 B

__device__ __forceinline__ unsigned int bf16_rne(float f) {
    const unsigned int u = __float_as_uint(f);
    return (u + 0x7fffu + ((u >> 16) & 1u)) >> 16;
}

// Kernel 1 (fused prep): blocks [0,512) do per-(t,d) argmax -> packed table;
// blocks [512,1024) convert responses fp32 -> packed bf16 pairs (RNE).
__global__ __launch_bounds__(256) void prep_kernel(
    const float* __restrict__ fw,      // (T, D, F)
    const float* __restrict__ thr,     // (T, D)
    const float* __restrict__ resp,    // (T*L*C)
    FP* __restrict__ packed,           // (T*D)
    unsigned int* __restrict__ rb)     // (T*L*C/2) bf16 pairs
{
    if (blockIdx.x < 512) {
        // argmax over F=512, first-occurrence tie-break (jnp.argmax)
        const int wave = threadIdx.x >> 6;
        const int lane = threadIdx.x & 63;
        const int row  = blockIdx.x * 4 + wave;          // [0, T*D)
        const float* base = fw + (size_t)row * F;

        float best = -INFINITY;
        int bidx = 0;
#pragma unroll
        for (int k = 0; k < F / 64; ++k) {
            const int idx = lane + k * 64;
            const float v = base[idx];
            if (v > best) { best = v; bidx = idx; }
        }
#pragma unroll
        for (int off = 32; off >= 1; off >>= 1) {
            const float ov = __shfl_xor(best, off);
            const int   oi = __shfl_xor(bidx, off);
            if (ov > best || (ov == best && oi < bidx)) { best = ov; bidx = oi; }
        }
        if (lane == 0) {
            FP p;
            p.fidx = bidx;
            p.thr  = thr[row];
            packed[row] = p;
        }
    } else {
        // responses fp32 -> bf16, 8 floats per thread
        const int i = (blockIdx.x - 512) * 256 + threadIdx.x;
        const float4* s = reinterpret_cast<const float4*>(resp) + i * 2;
        const float4 a = s[0], b = s[1];
        uint4 o;
        o.x = bf16_rne(a.x) | (bf16_rne(a.y) << 16);
        o.y = bf16_rne(a.z) | (bf16_rne(a.w) << 16);
        o.z = bf16_rne(b.x) | (bf16_rne(b.y) << 16);
        o.w = bf16_rne(b.z) | (bf16_rne(b.w) << 16);
        reinterpret_cast<uint4*>(rb)[i] = o;
    }
}

// Kernel 2: 8 samples per block (2048 blocks), one barrier, then each wave
// handles TWO samples end-to-end (2x gather payload per wave):
//   decide: lane computes trees 4*lane..4*lane+3 for both samples (shared
//           tbl b128 reads), packing 2 decision words;
//   exchange: 8 shfls per sample;
//   gather: lane = (slot=lane>>1, h=lane&1); 2 lanes cover one 32 B bf16
//           leaf row; 8 uint4 loads per sample (16 total, 16 B each, all in
//           flight via named register arrays);
//   reduce: butterfly over slot bits; lanes 0-3 store 2x f32x4 each.
__global__ __launch_bounds__(256, 4) void forest_kernel(
    const float* __restrict__ x,            // (B, F)
    const FP* __restrict__ packed,          // (T*D)
    const unsigned short* __restrict__ rb,  // bf16 (T, L, C)
    float* __restrict__ out)                // (B, C)
{
    __shared__ float xrow[8][F];   // 16 KB
    __shared__ int2  tbl[D][T];    // 16 KB: tbl[d][t] = {fidx, thr-bits}

    const int b0  = blockIdx.x * 8;
    const int tid = threadIdx.x;

    // Stage x rows: 1024 float4, 4 per thread, coalesced.
    {
        const float4* xs = reinterpret_cast<const float4*>(x + (size_t)b0 * F);
        float4* xl = reinterpret_cast<float4*>(&xrow[0][0]);
        xl[tid]       = xs[tid];
        xl[tid + 256] = xs[tid + 256];
        xl[tid + 512] = xs[tid + 512];
        xl[tid + 768] = xs[tid + 768];
    }
    // Stage node table transposed: thread tid reads tree tid's row (64 B
    // coalesced) and scatters to tbl[d][tid].
    {
        const int4* tp = reinterpret_cast<const int4*>(packed + (size_t)tid * D);
        const int4 q0 = tp[0], q1 = tp[1], q2 = tp[2], q3 = tp[3];
        tbl[0][tid] = make_int2(q0.x, q0.y);
        tbl[1][tid] = make_int2(q0.z, q0.w);
        tbl[2][tid] = make_int2(q1.x, q1.y);
        tbl[3][tid] = make_int2(q1.z, q1.w);
        tbl[4][tid] = make_int2(q2.x, q2.y);
        tbl[5][tid] = make_int2(q2.z, q2.w);
        tbl[6][tid] = make_int2(q3.x, q3.y);
        tbl[7][tid] = make_int2(q3.z, q3.w);
    }
    __syncthreads();   // the ONLY barrier

    const int w    = tid >> 6;
    const int lane = tid & 63;
    const int sA   = b0 + 2 * w;        // wave's two samples
    const int sB   = sA + 1;

    // ---- decide: trees 4*lane..4*lane+3, both samples ----
    const float* xA = &xrow[2 * w][0];
    const float* xB = &xrow[2 * w + 1][0];
    unsigned int decA = 0, decB = 0;    // byte j = decision of tree 4*lane+j
#pragma unroll
    for (int d = 0; d < D; ++d) {
        const int4 a = *reinterpret_cast<const int4*>(&tbl[d][4 * lane]);
        const int4 b = *reinterpret_cast<const int4*>(&tbl[d][4 * lane + 2]);
        const float t0 = __int_as_float(a.y), t1 = __int_as_float(a.w);
        const float t2 = __int_as_float(b.y), t3 = __int_as_float(b.w);
        const unsigned int bit = 128u >> d;       // powers = 2^(D-1-d)
        if (xA[a.x] > t0) decA |= bit;
        if (xA[a.z] > t1) decA |= bit << 8;
        if (xA[b.x] > t2) decA |= bit << 16;
        if (xA[b.z] > t3) decA |= bit << 24;
        if (xB[a.x] > t0) decB |= bit;
        if (xB[a.z] > t1) decB |= bit << 8;
        if (xB[b.x] > t2) decB |= bit << 16;
        if (xB[b.z] > t3) decB |= bit << 24;
    }

    // ---- exchange: slot = lane>>1 owns tree 32*kk+slot at load kk.
    // source lane = (32*kk+slot)>>2 = 8*kk + (slot>>2); byte = slot&3.
    const int slot = lane >> 1;
    const int h    = lane & 1;                    // half-row selector
    const int srcb = slot >> 2;
    const int bsel = (slot & 3) * 8;
    int dwA[8], dwB[8];
#pragma unroll
    for (int kk = 0; kk < 8; ++kk) {
        dwA[kk] = __shfl((int)decA, 8 * kk + srcb);
        dwB[kk] = __shfl((int)decB, 8 * kk + srcb);
    }

    // ---- gather: ushort offset = tree<<12 | dd<<4 | h<<3; uint4 = 8 bf16 ----
    const int hoff = h << 3;
    uint4 rA[8], rB[8];
#pragma unroll
    for (int kk = 0; kk < 8; ++kk) {
        const int ddA = (dwA[kk] >> bsel) & 255;
        const int ddB = (dwB[kk] >> bsel) & 255;
        const int tb  = ((kk << 5) + slot) << 12;
        rA[kk] = *reinterpret_cast<const uint4*>(rb + tb + (ddA << 4) + hoff);
        rB[kk] = *reinterpret_cast<const uint4*>(rb + tb + (ddB << 4) + hoff);
    }

    // ---- unpack + accumulate (channels hoff..hoff+7) ----
    float accA[8] = {0, 0, 0, 0, 0, 0, 0, 0};
    float accB[8] = {0, 0, 0, 0, 0, 0, 0, 0};
#pragma unroll
    for (int kk = 0; kk < 8; ++kk) {
        accA[0] += __uint_as_float(rA[kk].x << 16);
        accA[1] += __uint_as_float(rA[kk].x & 0xffff0000u);
        accA[2] += __uint_as_float(rA[kk].y << 16);
        accA[3] += __uint_as_float(rA[kk].y & 0xffff0000u);
        accA[4] += __uint_as_float(rA[kk].z << 16);
        accA[5] += __uint_as_float(rA[kk].z & 0xffff0000u);
        accA[6] += __uint_as_float(rA[kk].w << 16);
        accA[7] += __uint_as_float(rA[kk].w & 0xffff0000u);
        accB[0] += __uint_as_float(rB[kk].x << 16);
        accB[1] += __uint_as_float(rB[kk].x & 0xffff0000u);
        accB[2] += __uint_as_float(rB[kk].y << 16);
        accB[3] += __uint_as_float(rB[kk].y & 0xffff0000u);
        accB[4] += __uint_as_float(rB[kk].z << 16);
        accB[5] += __uint_as_float(rB[kk].z & 0xffff0000u);
        accB[6] += __uint_as_float(rB[kk].w << 16);
        accB[7] += __uint_as_float(rB[kk].w & 0xffff0000u);
    }

    // ---- reduce over slot bits (lane bits 1..5) ----
#pragma unroll
    for (int off = 2; off <= 32; off <<= 1) {
#pragma unroll
        for (int j = 0; j < 8; ++j) {
            accA[j] += __shfl_xor(accA[j], off);
            accB[j] += __shfl_xor(accB[j], off);
        }
    }

    // lanes 0,1 -> sample A halves; lanes 2,3 -> sample B halves.
    const float sc = 1.0f / T;
    if (lane < 2) {
        f32x4 v0 = { accA[0] * sc, accA[1] * sc, accA[2] * sc, accA[3] * sc };
        f32x4 v1 = { accA[4] * sc, accA[5] * sc, accA[6] * sc, accA[7] * sc };
        float* p = out + ((size_t)sA << 4) + (h << 3);
        *reinterpret_cast<f32x4*>(p)     = v0;
        *reinterpret_cast<f32x4*>(p + 4) = v1;
    } else if (lane < 4) {
        f32x4 v0 = { accB[0] * sc, accB[1] * sc, accB[2] * sc, accB[3] * sc };
        f32x4 v1 = { accB[4] * sc, accB[5] * sc, accB[6] * sc, accB[7] * sc };
        float* p = out + ((size_t)sB << 4) + (h << 3);
        *reinterpret_cast<f32x4*>(p)     = v0;
        *reinterpret_cast<f32x4*>(p + 4) = v1;
    }
}

extern "C" void kernel_launch(void* const* d_in, const int* in_sizes, int n_in,
                              void* d_out, int out_size, void* d_ws, size_t ws_size,
                              hipStream_t stream) {
    const float* x         = (const float*)d_in[0];  // (B, F)
    const float* fw        = (const float*)d_in[1];  // (T, D, F)
    const float* thr       = (const float*)d_in[2];  // (T, D)
    const float* responses = (const float*)d_in[3];  // (T, L, C)
    float* out             = (float*)d_out;          // (B, C)

    FP* packed        = (FP*)d_ws;                                 // 16 KB
    unsigned int* rb  = (unsigned int*)((char*)d_ws + (1 << 16));  // 2 MB bf16

    prep_kernel<<<1024, 256, 0, stream>>>(fw, thr, responses, packed, rb);
    forest_kernel<<<B / 8, 256, 0, stream>>>(x, packed,
                                             (const unsigned short*)rb, out);
}